// Round 12
// baseline (60.393 us; speedup 1.0000x reference)
//
#include <hip/hip_runtime.h>
#include <hip/hip_bf16.h>

#define M_TOT 16384   // B*T*H*W = 2*8*32*32
#define D_    256
#define K_DIM 256

typedef __attribute__((ext_vector_type(4))) float f32x4;
typedef __attribute__((ext_vector_type(8))) short s16x8;
typedef __attribute__((ext_vector_type(4))) short s16x4;

typedef const __attribute__((address_space(1))) void* gptr_t;
typedef __attribute__((address_space(3))) void* lptr_t;

__device__ __forceinline__ unsigned short f2bf(float f) {
  unsigned x = __float_as_uint(f);
  return (unsigned short)((x + 0x7fffu + ((x >> 16) & 1u)) >> 16);
}
__device__ __forceinline__ float bf2f(short s) {
  return __uint_as_float(((unsigned)(unsigned short)s) << 16);
}

// ---------- weight transpose + cast: Wt[outcol][k], 256 blocks ----------
__global__ __launch_bounds__(256) void wtrans_kernel(
    const float* __restrict__ wq, const float* __restrict__ wk,
    const float* __restrict__ wv, const float* __restrict__ wo,
    unsigned short* __restrict__ wt_qkv, unsigned short* __restrict__ wt_o) {
  __shared__ float tile[32][33];
  int tid = threadIdx.x;
  int bid = blockIdx.x;            // 0..255
  int z   = bid >> 6;              // 0=wq 1=wk 2=wv 3=wo
  int rem = bid & 63;
  int k0 = (rem & 7) * 32, n0 = (rem >> 3) * 32;
  int tx = tid & 31, ty = tid >> 5;  // (32,8)
  const float* src = (z == 0) ? wq : (z == 1) ? wk : (z == 2) ? wv : wo;
#pragma unroll
  for (int i = 0; i < 4; ++i) {
    int r = ty + i * 8;
    tile[r][tx] = src[(size_t)(k0 + r) * D_ + n0 + tx];
  }
  __syncthreads();
  unsigned short* dst = (z < 3) ? (wt_qkv + (size_t)(z * 256 + n0) * K_DIM + k0)
                                : (wt_o + (size_t)n0 * K_DIM + k0);
#pragma unroll
  for (int i = 0; i < 4; ++i) {
    int r = ty + i * 8;
    dst[(size_t)r * K_DIM + tx] = f2bf(tile[tx][r]);
  }
}

// ------- Fused LN + QKV GEMM, prologue-staged A (fixes R10's in-loop staging) -------
// 128x128 tile, 4 waves. Grid 768, XCD-bijective swizzle.
// LDS 80KB: Afull [128][512B] bf16 swizzled (64KB, staged ONCE with LN in
// prologue) + Bsm [128][128B] (16KB, global_load_lds per K-step). 2 blocks/CU.
__global__ __launch_bounds__(256, 2) void lngemm_qkv_kernel(
    const float* __restrict__ x, const float* __restrict__ g, const float* __restrict__ b,
    const unsigned short* __restrict__ Bt,
    const float* __restrict__ b0, const float* __restrict__ b1, const float* __restrict__ b2,
    unsigned short* __restrict__ C) {
  __shared__ __align__(16) char smem[81920];
  char* Afull = smem;            // [128][512B], XOR-swizzled within 128B groups
  char* Bsm   = smem + 65536;    // [128][128B], swizzled
  const int tid  = threadIdx.x;
  const int wid  = tid >> 6;
  const int lane = tid & 63;
  int lin = blockIdx.x;
  int swz = (lin & 7) * 96 + (lin >> 3);   // bijective XCD swizzle
  const int m0 = (swz / 6) * 128;
  const int n0 = (swz % 6) * 128;
  const int wave_m = wid >> 1;
  const int wave_n = wid & 1;

  // ---- LN prologue: 2 threads/row. Pass 1 stats, pass 2 apply -> Afull ----
  {
    const int row   = tid >> 1;
    const int halfc = (tid & 1) * 128;           // element offset
    const f32x4* px = (const f32x4*)(x + (size_t)(m0 + row) * D_ + halfc);
    float s = 0.f, s2 = 0.f;
#pragma unroll
    for (int i = 0; i < 32; ++i) {
      f32x4 v = px[i];
#pragma unroll
      for (int e = 0; e < 4; ++e) { s += v[e]; s2 += v[e] * v[e]; }
    }
    s  += __shfl_xor(s, 1);
    s2 += __shfl_xor(s2, 1);
    float mu   = s * (1.0f / 256.0f);
    float rstd = rsqrtf(s2 * (1.0f / 256.0f) - mu * mu + 1e-5f);
    float negc = -mu * rstd;
    const f32x4* pg = (const f32x4*)(g + halfc);
    const f32x4* pb = (const f32x4*)(b + halfc);
#pragma unroll
    for (int i = 0; i < 16; ++i) {               // 8 elems/iter (L1-hot re-read)
      f32x4 v0 = px[2 * i], v1 = px[2 * i + 1];
      f32x4 g0 = pg[2 * i], g1 = pg[2 * i + 1];
      f32x4 q0 = pb[2 * i], q1 = pb[2 * i + 1];
      s16x8 o8;
#pragma unroll
      for (int e = 0; e < 4; ++e) {
        o8[e]     = (short)f2bf(fmaf(fmaf(v0[e], rstd, negc), g0[e], q0[e]));
        o8[e + 4] = (short)f2bf(fmaf(fmaf(v1[e], rstd, negc), g1[e], q1[e]));
      }
      int byte = (halfc + i * 8) * 2;            // 0..511
      *(s16x8*)(Afull + row * 512 + (byte ^ ((row & 7) << 4))) = o8;
    }
  }

  f32x4 acc[4][4] = {};

  for (int ks = 0; ks < 4; ++ks) {
    const int kk0 = ks * 64;
    __syncthreads();  // ks=0: Afull visible; ks>0: prev Bsm reads done
    // ---- B staging only: global_load_lds, 16KB in 4 sweeps ----
#pragma unroll
    for (int it = 0; it < 4; ++it) {
      int base     = it * 4096 + wid * 1024;
      int lane_lin = base + lane * 16;
      int row  = lane_lin >> 7;
      int off  = lane_lin & 127;
      int soff = off ^ ((row & 7) << 4);
      const char* gb2 = (const char*)(Bt + (size_t)(n0 + row) * K_DIM + kk0) + soff;
      __builtin_amdgcn_global_load_lds((gptr_t)gb2, (lptr_t)(Bsm + base), 16, 0, 0);
    }
    __syncthreads();  // drains vmcnt

#pragma unroll
    for (int kk = 0; kk < 2; ++kk) {
      s16x8 af[4], bf[4];
#pragma unroll
      for (int m = 0; m < 4; ++m) {
        int r    = wave_m * 64 + m * 16 + (lane & 15);
        int byte = ks * 128 + kk * 64 + ((lane >> 4) * 16);
        af[m] = *(const s16x8*)(Afull + r * 512 + (byte ^ ((r & 7) << 4)));
      }
#pragma unroll
      for (int n = 0; n < 4; ++n) {
        int r    = wave_n * 64 + n * 16 + (lane & 15);
        int byte = kk * 64 + ((lane >> 4) * 16);
        bf[n] = *(const s16x8*)(Bsm + r * 128 + (byte ^ ((r & 7) << 4)));
      }
#pragma unroll
      for (int m = 0; m < 4; ++m)
#pragma unroll
        for (int n = 0; n < 4; ++n)
          acc[m][n] = __builtin_amdgcn_mfma_f32_16x16x32_bf16(af[m], bf[n], acc[m][n], 0, 0, 0);
    }
  }

  const int c0 = lane & 15;
  const int r0 = (lane >> 4) * 4;
#pragma unroll
  for (int m = 0; m < 4; ++m) {
#pragma unroll
    for (int n = 0; n < 4; ++n) {
      int row = m0 + wave_m * 64 + m * 16 + r0;
      int col = n0 + wave_n * 64 + n * 16 + c0;
      const float* bias = (col < 256) ? b0 : (col < 512) ? b1 : b2;
      float bb = bias[col & 255];
#pragma unroll
      for (int r = 0; r < 4; ++r)
        C[(size_t)(row + r) * 768 + col] = f2bf(acc[m][n][r] + bb);
    }
  }
}

// -------- Fused local-attention + output GEMM + bias + residual (R7-proven) --------
__global__ __launch_bounds__(512, 4) void attn_ogemm_kernel(
    const unsigned short* __restrict__ qkv, const unsigned short* __restrict__ wto,
    const float* __restrict__ bo, const float* __restrict__ x,
    float* __restrict__ out) {
  __shared__ __align__(16) char smem[65536];
  char* Halo = smem;           // 48KB: K-halo in phase 1; Bsm (32KB) in phase 2
  char* Asm  = smem + 49152;   // [32 tok][512B], XOR-swizzled
  const int tid  = threadIdx.x;
  const int wid  = tid >> 6;
  const int lane = tid & 63;
  int bswz = (blockIdx.x & 7) * 64 + (blockIdx.x >> 3);
  const int bt = bswz >> 5;
  const int h  = bswz & 31;
  const int t0 = bswz * 32;
  const size_t img = (size_t)bt << 10;

  int srow[3];
  srow[0] = max(h - 1, 0); srow[1] = h; srow[2] = min(h + 1, 31);

  // ---- Phase 1: K-halo -> LDS (48 x 1KB chunks) ----
#pragma unroll
  for (int sweep = 0; sweep < 6; ++sweep) {
    int chunk = sweep * 8 + wid;
    int slot = chunk >> 4, t2 = chunk & 15;
    int tokw = t2 * 2 + (lane >> 5);
    int off  = (lane & 31) * 16;
    size_t grow = img + (size_t)srow[slot] * 32 + tokw;
    const char* ga = (const char*)qkv + grow * 1536 + 512 + off;  // K at elem 256
    __builtin_amdgcn_global_load_lds((gptr_t)ga, (lptr_t)(Halo + chunk * 1024), 16, 0, 0);
  }
  s16x4 qr4[4];
#pragma unroll
  for (int i = 0; i < 4; ++i)
    qr4[i] = *(const s16x4*)(qkv + (size_t)(t0 + wid * 4 + i) * 768 + lane * 4);
  s16x4 vreg[3][6];
#pragma unroll
  for (int s = 0; s < 3; ++s) {
#pragma unroll
    for (int cr = 0; cr < 6; ++cr) {
      int cc = min(max(wid * 4 - 1 + cr, 0), 31);
      vreg[s][cr] = *(const s16x4*)(qkv + (img + (size_t)srow[s] * 32 + cc) * 768 +
                                    512 + lane * 4);
    }
  }
  __syncthreads();

  // ---- scores + softmax + PV per token; head = lane>>3, d = lane*4 ----
#pragma unroll
  for (int i = 0; i < 4; ++i) {
    int tloc = wid * 4 + i;
    f32x4 q;
#pragma unroll
    for (int e = 0; e < 4; ++e) q[e] = bf2f(qr4[i][e]);
    float sc[9];
#pragma unroll
    for (int s = 0; s < 3; ++s) {
#pragma unroll
      for (int dw = -1; dw <= 1; ++dw) {
        const int j = s * 3 + (dw + 1);
        int cw = min(max(tloc + dw, 0), 31);
        s16x4 kr = *(const s16x4*)(Halo + (s * 32 + cw) * 512 + lane * 8);
        float p = 0.f;
#pragma unroll
        for (int e = 0; e < 4; ++e) p += q[e] * bf2f(kr[e]);
        p += __shfl_xor(p, 1);
        p += __shfl_xor(p, 2);
        p += __shfl_xor(p, 4);
        sc[j] = p * 0.17677669529663687f;  // 1/sqrt(32)
      }
    }
    float mx = sc[0];
#pragma unroll
    for (int j = 1; j < 9; ++j) mx = fmaxf(mx, sc[j]);
    float den = 0.f;
#pragma unroll
    for (int j = 0; j < 9; ++j) { sc[j] = __expf(sc[j] - mx); den += sc[j]; }
    float inv = 1.0f / den;
    f32x4 o = {};
#pragma unroll
    for (int s = 0; s < 3; ++s) {
#pragma unroll
      for (int dw = -1; dw <= 1; ++dw) {
        const int j = s * 3 + (dw + 1);
        float wj = sc[j] * inv;
        s16x4 vr = vreg[s][i + dw + 1];
#pragma unroll
        for (int e = 0; e < 4; ++e) o[e] += wj * bf2f(vr[e]);
      }
    }
    s16x4 ov;
#pragma unroll
    for (int e = 0; e < 4; ++e) ov[e] = (short)f2bf(o[e]);
    int byte = (lane * 8) ^ ((tloc & 7) << 4);
    *(s16x4*)(Asm + tloc * 512 + byte) = ov;
  }

  // ---- Phase 2: out-GEMM. 8 waves = 2(m) x 4(n); wave-tile 16x64 ----
  const int wave_m = wid >> 2;
  const int wave_n = wid & 3;
  f32x4 acc[4] = {};

  for (int ks = 0; ks < 4; ++ks) {
    __syncthreads();
#pragma unroll
    for (int it = 0; it < 4; ++it) {
      int base     = it * 8192 + wid * 1024;
      int lane_lin = base + lane * 16;
      int row  = lane_lin >> 7;
      int off  = lane_lin & 127;
      int soff = off ^ ((row & 7) << 4);
      const char* gb = (const char*)(wto + (size_t)row * K_DIM + ks * 64) + soff;
      __builtin_amdgcn_global_load_lds((gptr_t)gb, (lptr_t)(Halo + base), 16, 0, 0);
    }
    __syncthreads();

#pragma unroll
    for (int kk = 0; kk < 2; ++kk) {
      s16x8 af, bf[4];
      {
        int r    = wave_m * 16 + (lane & 15);
        int byte = ks * 128 + kk * 64 + ((lane >> 4) * 16);
        af = *(const s16x8*)(Asm + r * 512 + (byte ^ ((r & 7) << 4)));
      }
#pragma unroll
      for (int n = 0; n < 4; ++n) {
        int r    = wave_n * 64 + n * 16 + (lane & 15);
        int byte = kk * 64 + ((lane >> 4) * 16);
        bf[n] = *(const s16x8*)(Halo + r * 128 + (byte ^ ((r & 7) << 4)));
      }
#pragma unroll
      for (int n = 0; n < 4; ++n)
        acc[n] = __builtin_amdgcn_mfma_f32_16x16x32_bf16(af, bf[n], acc[n], 0, 0, 0);
    }
  }

  const int c0 = lane & 15;
  const int r0 = (lane >> 4) * 4;
#pragma unroll
  for (int n = 0; n < 4; ++n) {
    int col = wave_n * 64 + n * 16 + c0;
    float bb = bo[col];
#pragma unroll
    for (int r = 0; r < 4; ++r) {
      int row = t0 + wave_m * 16 + r0 + r;
      out[(size_t)row * D_ + col] = acc[n][r] + bb + x[(size_t)row * D_ + col];
    }
  }
}

extern "C" void kernel_launch(void* const* d_in, const int* in_sizes, int n_in,
                              void* d_out, int out_size, void* d_ws, size_t ws_size,
                              hipStream_t stream) {
  const float* x  = (const float*)d_in[0];
  const float* lg = (const float*)d_in[1];
  const float* lb = (const float*)d_in[2];
  const float* wq = (const float*)d_in[3];
  const float* bq = (const float*)d_in[4];
  const float* wk = (const float*)d_in[5];
  const float* bk = (const float*)d_in[6];
  const float* wv = (const float*)d_in[7];
  const float* bv = (const float*)d_in[8];
  const float* wo = (const float*)d_in[9];
  const float* bo = (const float*)d_in[10];
  float* out = (float*)d_out;

  char* ws = (char*)d_ws;
  unsigned short* qkv   = (unsigned short*)(ws + 8388608);     // 16384*768*2
  unsigned short* wtqkv = (unsigned short*)(ws + 33554432);    // 768*256*2
  unsigned short* wto   = (unsigned short*)(ws + 33947648);    // 256*256*2

  wtrans_kernel<<<256, 256, 0, stream>>>(wq, wk, wv, wo, wtqkv, wto);
  lngemm_qkv_kernel<<<768, 256, 0, stream>>>(x, lg, lb, wtqkv, bq, bk, bv, qkv);
  attn_ogemm_kernel<<<512, 512, 0, stream>>>(qkv, wto, bo, x, out);
}

// Round 13
// 53.511 us; speedup vs baseline: 1.1286x; 1.1286x over previous
//
#include <hip/hip_runtime.h>
#include <hip/hip_bf16.h>

#define M_TOT 16384   // B*T*H*W = 2*8*32*32
#define D_    256
#define K_DIM 256

typedef __attribute__((ext_vector_type(4))) float f32x4;
typedef __attribute__((ext_vector_type(8))) short s16x8;
typedef __attribute__((ext_vector_type(4))) short s16x4;

typedef const __attribute__((address_space(1))) void* gptr_t;
typedef __attribute__((address_space(3))) void* lptr_t;

__device__ __forceinline__ unsigned short f2bf(float f) {
  unsigned x = __float_as_uint(f);
  return (unsigned short)((x + 0x7fffu + ((x >> 16) & 1u)) >> 16);
}
__device__ __forceinline__ float bf2f(short s) {
  return __uint_as_float(((unsigned)(unsigned short)s) << 16);
}

// ---------- prep: blocks [0,4096) = LayerNorm, [4096,4352) = weight transpose ----------
__global__ __launch_bounds__(256) void prep_kernel(
    const float* __restrict__ x, const float* __restrict__ g, const float* __restrict__ b,
    unsigned short* __restrict__ xn,
    const float* __restrict__ wq, const float* __restrict__ wk,
    const float* __restrict__ wv, const float* __restrict__ wo,
    unsigned short* __restrict__ wt_qkv, unsigned short* __restrict__ wt_o) {
  __shared__ float tile[32][33];
  int tid = threadIdx.x;
  if (blockIdx.x < 4096) {
    int tok  = blockIdx.x * 4 + (tid >> 6);
    int lane = tid & 63;
    f32x4 v = ((const f32x4*)(x + (size_t)tok * D_))[lane];
    float s = 0.f, s2 = 0.f;
#pragma unroll
    for (int i = 0; i < 4; ++i) { s += v[i]; s2 += v[i] * v[i]; }
#pragma unroll
    for (int o = 1; o < 64; o <<= 1) { s += __shfl_xor(s, o); s2 += __shfl_xor(s2, o); }
    float mu   = s * (1.0f / 256.0f);
    float rstd = rsqrtf(s2 * (1.0f / 256.0f) - mu * mu + 1e-5f);
    f32x4 gv = ((const f32x4*)g)[lane];
    f32x4 bv = ((const f32x4*)b)[lane];
    s16x4 o4;
#pragma unroll
    for (int i = 0; i < 4; ++i) o4[i] = (short)f2bf((v[i] - mu) * rstd * gv[i] + bv[i]);
    ((s16x4*)(xn + (size_t)tok * D_))[lane] = o4;
  } else {
    int bid = blockIdx.x - 4096;     // 0..255
    int z   = bid >> 6;              // 0=wq 1=wk 2=wv 3=wo
    int rem = bid & 63;
    int k0 = (rem & 7) * 32, n0 = (rem >> 3) * 32;
    int tx = tid & 31, ty = tid >> 5;  // (32,8)
    const float* src = (z == 0) ? wq : (z == 1) ? wk : (z == 2) ? wv : wo;
#pragma unroll
    for (int i = 0; i < 4; ++i) {
      int r = ty + i * 8;
      tile[r][tx] = src[(size_t)(k0 + r) * D_ + n0 + tx];
    }
    __syncthreads();
    unsigned short* dst = (z < 3) ? (wt_qkv + (size_t)(z * 256 + n0) * K_DIM + k0)
                                  : (wt_o + (size_t)n0 * K_DIM + k0);
#pragma unroll
    for (int i = 0; i < 4; ++i) {
      int r = ty + i * 8;
      dst[(size_t)r * K_DIM + tx] = f2bf(tile[tx][r]);
    }
  }
}

// ---------------- QKV GEMM: C[M][768] = A[M][256] * Bt[768][256]^T -----------
// 128x128 tile, BK=64, 4 waves (2x2). Grid 768, XCD-bijective swizzle. (R7-proven.)
__global__ __launch_bounds__(256) void gemm_qkv_kernel(
    const unsigned short* __restrict__ A, const unsigned short* __restrict__ Bt,
    const float* __restrict__ b0, const float* __restrict__ b1, const float* __restrict__ b2,
    unsigned short* __restrict__ C) {
  __shared__ __align__(16) char smem[32768];
  char* Asm = smem;            // [128][64] bf16, 128B rows, swizzled
  char* Bsm = smem + 16384;
  const int tid  = threadIdx.x;
  const int wid  = tid >> 6;
  const int lane = tid & 63;
  int lin = blockIdx.y * 6 + blockIdx.x;
  int swz = (lin & 7) * 96 + (lin >> 3);   // 768 blocks, bijective XCD swizzle
  const int m0 = (swz / 6) * 128;
  const int n0 = (swz % 6) * 128;
  const int wave_m = wid >> 1;
  const int wave_n = wid & 1;

  f32x4 acc[4][4] = {};

  for (int ks = 0; ks < 4; ++ks) {
    const int kk0 = ks * 64;
    __syncthreads();
#pragma unroll
    for (int it = 0; it < 4; ++it) {
      int base     = (it * 256 + wid * 64) * 16;
      int lane_lin = base + lane * 16;
      int row  = lane_lin >> 7;
      int off  = lane_lin & 127;
      int soff = off ^ ((row & 7) << 4);
      const char* ga = (const char*)(A + (size_t)(m0 + row) * K_DIM + kk0) + soff;
      const char* gb = (const char*)(Bt + (size_t)(n0 + row) * K_DIM + kk0) + soff;
      __builtin_amdgcn_global_load_lds((gptr_t)ga, (lptr_t)(Asm + base), 16, 0, 0);
      __builtin_amdgcn_global_load_lds((gptr_t)gb, (lptr_t)(Bsm + base), 16, 0, 0);
    }
    __syncthreads();

#pragma unroll
    for (int kk = 0; kk < 2; ++kk) {
      s16x8 af[4], bf[4];
#pragma unroll
      for (int m = 0; m < 4; ++m) {
        int r    = wave_m * 64 + m * 16 + (lane & 15);
        int byte = kk * 64 + ((lane >> 4) * 16);
        af[m] = *(const s16x8*)(Asm + r * 128 + (byte ^ ((r & 7) << 4)));
      }
#pragma unroll
      for (int n = 0; n < 4; ++n) {
        int r    = wave_n * 64 + n * 16 + (lane & 15);
        int byte = kk * 64 + ((lane >> 4) * 16);
        bf[n] = *(const s16x8*)(Bsm + r * 128 + (byte ^ ((r & 7) << 4)));
      }
#pragma unroll
      for (int m = 0; m < 4; ++m)
#pragma unroll
        for (int n = 0; n < 4; ++n)
          acc[m][n] = __builtin_amdgcn_mfma_f32_16x16x32_bf16(af[m], bf[n], acc[m][n], 0, 0, 0);
    }
  }

  const int c0 = lane & 15;
  const int r0 = (lane >> 4) * 4;
#pragma unroll
  for (int m = 0; m < 4; ++m) {
#pragma unroll
    for (int n = 0; n < 4; ++n) {
      int row = m0 + wave_m * 64 + m * 16 + r0;
      int col = n0 + wave_n * 64 + n * 16 + c0;
      const float* bias = (col < 256) ? b0 : (col < 512) ? b1 : b2;
      float bb = bias[col & 255];
#pragma unroll
      for (int r = 0; r < 4; ++r)
        C[(size_t)(row + r) * 768 + col] = f2bf(acc[m][n][r] + bb);
    }
  }
}

// ---- phase-2 helpers: B-fragments of Wo^T in REGISTERS (static indices) ----
template <int KS>
__device__ __forceinline__ void load_b(const unsigned short* __restrict__ wto,
                                       int brow, int bcol, s16x8* buf) {
#pragma unroll
  for (int n = 0; n < 4; ++n)
#pragma unroll
    for (int kk = 0; kk < 2; ++kk)
      buf[n * 2 + kk] = *(const s16x8*)(wto + (size_t)(brow + n * 16) * K_DIM +
                                        KS * 64 + kk * 32 + bcol);
}
template <int KS>
__device__ __forceinline__ void comp_b(const char* Asm, int wave_m, int lane,
                                       const s16x8* buf, f32x4* acc) {
#pragma unroll
  for (int kk = 0; kk < 2; ++kk) {
    int r    = wave_m * 16 + (lane & 15);
    int byte = KS * 128 + kk * 64 + ((lane >> 4) * 16);
    s16x8 af = *(const s16x8*)(Asm + r * 512 + (byte ^ ((r & 7) << 4)));
#pragma unroll
    for (int n = 0; n < 4; ++n)
      acc[n] = __builtin_amdgcn_mfma_f32_16x16x32_bf16(af, buf[n * 2 + kk], acc[n], 0, 0, 0);
  }
}

// -------- Fused local-attention + output GEMM + bias + residual --------------
// Block = one image row (32 tokens), 512 threads (8 waves). Grid 512 (2/CU).
// Phase 1: K-halo (48KB) -> LDS; V (18 rows/wave) + Q -> regs; B-frags(ks=0) -> regs.
// Phase 2: C[32][256] = Asm @ Wo^T with REGISTER-resident B (no LDS staging,
//          no per-ks barriers); pipelined LOADB(k+1)/COMPUTE(k).
__global__ __launch_bounds__(512, 4) void attn_ogemm_kernel(
    const unsigned short* __restrict__ qkv, const unsigned short* __restrict__ wto,
    const float* __restrict__ bo, const float* __restrict__ x,
    float* __restrict__ out) {
  __shared__ __align__(16) char smem[65536];
  char* Halo = smem;           // 48KB K-halo
  char* Asm  = smem + 49152;   // [32 tok][512B], XOR-swizzled
  const int tid  = threadIdx.x;
  const int wid  = tid >> 6;
  const int lane = tid & 63;
  int bswz = (blockIdx.x & 7) * 64 + (blockIdx.x >> 3);
  const int bt = bswz >> 5;
  const int h  = bswz & 31;
  const int t0 = bswz * 32;
  const size_t img = (size_t)bt << 10;

  int srow[3];
  srow[0] = max(h - 1, 0); srow[1] = h; srow[2] = min(h + 1, 31);

  // ---- Phase 1: K-halo -> LDS (48 x 1KB chunks) ----
#pragma unroll
  for (int sweep = 0; sweep < 6; ++sweep) {
    int chunk = sweep * 8 + wid;
    int slot = chunk >> 4, t2 = chunk & 15;
    int tokw = t2 * 2 + (lane >> 5);
    int off  = (lane & 31) * 16;
    size_t grow = img + (size_t)srow[slot] * 32 + tokw;
    const char* ga = (const char*)qkv + grow * 1536 + 512 + off;  // K at elem 256
    __builtin_amdgcn_global_load_lds((gptr_t)ga, (lptr_t)(Halo + chunk * 1024), 16, 0, 0);
  }
  // Concurrently: Q (4 rows), V (3x6 neighbor rows), and ks=0 B-frags -> regs.
  s16x4 qr4[4];
#pragma unroll
  for (int i = 0; i < 4; ++i)
    qr4[i] = *(const s16x4*)(qkv + (size_t)(t0 + wid * 4 + i) * 768 + lane * 4);
  s16x4 vreg[3][6];
#pragma unroll
  for (int s = 0; s < 3; ++s) {
#pragma unroll
    for (int cr = 0; cr < 6; ++cr) {
      int cc = min(max(wid * 4 - 1 + cr, 0), 31);
      vreg[s][cr] = *(const s16x4*)(qkv + (img + (size_t)srow[s] * 32 + cc) * 768 +
                                    512 + lane * 4);
    }
  }
  const int wave_m = wid >> 2;
  const int wave_n = wid & 3;
  const int brow = wave_n * 64 + (lane & 15);
  const int bcol = (lane >> 4) * 8;
  s16x8 bufA[8], bufB[8];
  load_b<0>(wto, brow, bcol, bufA);
  __syncthreads();  // drains K-halo

  // ---- scores + softmax + PV per token; head = lane>>3, d = lane*4 ----
#pragma unroll
  for (int i = 0; i < 4; ++i) {
    int tloc = wid * 4 + i;
    f32x4 q;
#pragma unroll
    for (int e = 0; e < 4; ++e) q[e] = bf2f(qr4[i][e]);
    float sc[9];
#pragma unroll
    for (int s = 0; s < 3; ++s) {
#pragma unroll
      for (int dw = -1; dw <= 1; ++dw) {
        const int j = s * 3 + (dw + 1);
        int cw = min(max(tloc + dw, 0), 31);
        s16x4 kr = *(const s16x4*)(Halo + (s * 32 + cw) * 512 + lane * 8);
        float p = 0.f;
#pragma unroll
        for (int e = 0; e < 4; ++e) p += q[e] * bf2f(kr[e]);
        p += __shfl_xor(p, 1);
        p += __shfl_xor(p, 2);
        p += __shfl_xor(p, 4);
        sc[j] = p * 0.17677669529663687f;  // 1/sqrt(32)
      }
    }
    float mx = sc[0];
#pragma unroll
    for (int j = 1; j < 9; ++j) mx = fmaxf(mx, sc[j]);
    float den = 0.f;
#pragma unroll
    for (int j = 0; j < 9; ++j) { sc[j] = __expf(sc[j] - mx); den += sc[j]; }
    float inv = 1.0f / den;
    f32x4 o = {};
#pragma unroll
    for (int s = 0; s < 3; ++s) {
#pragma unroll
      for (int dw = -1; dw <= 1; ++dw) {
        const int j = s * 3 + (dw + 1);
        float wj = sc[j] * inv;
        s16x4 vr = vreg[s][i + dw + 1];   // static index
#pragma unroll
        for (int e = 0; e < 4; ++e) o[e] += wj * bf2f(vr[e]);
      }
    }
    s16x4 ov;
#pragma unroll
    for (int e = 0; e < 4; ++e) ov[e] = (short)f2bf(o[e]);
    int byte = (lane * 8) ^ ((tloc & 7) << 4);
    *(s16x4*)(Asm + tloc * 512 + byte) = ov;
  }
  __syncthreads();  // Asm visible to all waves (the ONLY phase-2 barrier)

  // ---- Phase 2: register-B pipelined GEMM, zero LDS staging ----
  f32x4 acc[4] = {};
  load_b<1>(wto, brow, bcol, bufB);
  comp_b<0>(Asm, wave_m, lane, bufA, acc);
  load_b<2>(wto, brow, bcol, bufA);
  comp_b<1>(Asm, wave_m, lane, bufB, acc);
  load_b<3>(wto, brow, bcol, bufB);
  comp_b<2>(Asm, wave_m, lane, bufA, acc);
  comp_b<3>(Asm, wave_m, lane, bufB, acc);

  const int c0 = lane & 15;
  const int r0 = (lane >> 4) * 4;
#pragma unroll
  for (int n = 0; n < 4; ++n) {
    int col = wave_n * 64 + n * 16 + c0;
    float bb = bo[col];
#pragma unroll
    for (int r = 0; r < 4; ++r) {
      int row = t0 + wave_m * 16 + r0 + r;
      out[(size_t)row * D_ + col] = acc[n][r] + bb + x[(size_t)row * D_ + col];
    }
  }
}

extern "C" void kernel_launch(void* const* d_in, const int* in_sizes, int n_in,
                              void* d_out, int out_size, void* d_ws, size_t ws_size,
                              hipStream_t stream) {
  const float* x  = (const float*)d_in[0];
  const float* lg = (const float*)d_in[1];
  const float* lb = (const float*)d_in[2];
  const float* wq = (const float*)d_in[3];
  const float* bq = (const float*)d_in[4];
  const float* wk = (const float*)d_in[5];
  const float* bk = (const float*)d_in[6];
  const float* wv = (const float*)d_in[7];
  const float* bv = (const float*)d_in[8];
  const float* wo = (const float*)d_in[9];
  const float* bo = (const float*)d_in[10];
  float* out = (float*)d_out;

  char* ws = (char*)d_ws;
  unsigned short* xn    = (unsigned short*)ws;                 // 16384*256*2
  unsigned short* qkv   = (unsigned short*)(ws + 8388608);     // 16384*768*2
  unsigned short* wtqkv = (unsigned short*)(ws + 33554432);    // 768*256*2
  unsigned short* wto   = (unsigned short*)(ws + 33947648);    // 256*256*2

  prep_kernel<<<4352, 256, 0, stream>>>(x, lg, lb, xn, wq, wk, wv, wo, wtqkv, wto);
  gemm_qkv_kernel<<<dim3(6, 128), 256, 0, stream>>>(xn, wtqkv, bq, bk, bv, qkv);
  attn_ogemm_kernel<<<512, 512, 0, stream>>>(qkv, wto, bo, x, out);
}

// Round 14
// 41.322 us; speedup vs baseline: 1.4615x; 1.2950x over previous
//
#include <hip/hip_runtime.h>
#include <hip/hip_bf16.h>

#define M_TOT 16384   // B*T*H*W = 2*8*32*32
#define D_    256
#define K_DIM 256

typedef __attribute__((ext_vector_type(4))) float f32x4;
typedef __attribute__((ext_vector_type(8))) short s16x8;
typedef __attribute__((ext_vector_type(4))) short s16x4;

typedef const __attribute__((address_space(1))) void* gptr_t;
typedef __attribute__((address_space(3))) void* lptr_t;

__device__ __forceinline__ unsigned short f2bf(float f) {
  unsigned x = __float_as_uint(f);
  return (unsigned short)((x + 0x7fffu + ((x >> 16) & 1u)) >> 16);
}
__device__ __forceinline__ float bf2f(short s) {
  return __uint_as_float(((unsigned)(unsigned short)s) << 16);
}

// ---------- prep: blocks [0,4096) = LayerNorm, [4096,4352) = weight transpose ----------
__global__ __launch_bounds__(256) void prep_kernel(
    const float* __restrict__ x, const float* __restrict__ g, const float* __restrict__ b,
    unsigned short* __restrict__ xn,
    const float* __restrict__ wq, const float* __restrict__ wk,
    const float* __restrict__ wv, const float* __restrict__ wo,
    unsigned short* __restrict__ wt_qkv, unsigned short* __restrict__ wt_o) {
  __shared__ float tile[32][33];
  int tid = threadIdx.x;
  if (blockIdx.x < 4096) {
    int tok  = blockIdx.x * 4 + (tid >> 6);
    int lane = tid & 63;
    f32x4 v = ((const f32x4*)(x + (size_t)tok * D_))[lane];
    float s = 0.f, s2 = 0.f;
#pragma unroll
    for (int i = 0; i < 4; ++i) { s += v[i]; s2 += v[i] * v[i]; }
#pragma unroll
    for (int o = 1; o < 64; o <<= 1) { s += __shfl_xor(s, o); s2 += __shfl_xor(s2, o); }
    float mu   = s * (1.0f / 256.0f);
    float rstd = rsqrtf(s2 * (1.0f / 256.0f) - mu * mu + 1e-5f);
    f32x4 gv = ((const f32x4*)g)[lane];
    f32x4 bv = ((const f32x4*)b)[lane];
    s16x4 o4;
#pragma unroll
    for (int i = 0; i < 4; ++i) o4[i] = (short)f2bf((v[i] - mu) * rstd * gv[i] + bv[i]);
    ((s16x4*)(xn + (size_t)tok * D_))[lane] = o4;
  } else {
    int bid = blockIdx.x - 4096;     // 0..255
    int z   = bid >> 6;              // 0=wq 1=wk 2=wv 3=wo
    int rem = bid & 63;
    int k0 = (rem & 7) * 32, n0 = (rem >> 3) * 32;
    int tx = tid & 31, ty = tid >> 5;  // (32,8)
    const float* src = (z == 0) ? wq : (z == 1) ? wk : (z == 2) ? wv : wo;
#pragma unroll
    for (int i = 0; i < 4; ++i) {
      int r = ty + i * 8;
      tile[r][tx] = src[(size_t)(k0 + r) * D_ + n0 + tx];
    }
    __syncthreads();
    unsigned short* dst = (z < 3) ? (wt_qkv + (size_t)(z * 256 + n0) * K_DIM + k0)
                                  : (wt_o + (size_t)n0 * K_DIM + k0);
#pragma unroll
    for (int i = 0; i < 4; ++i) {
      int r = ty + i * 8;
      dst[(size_t)r * K_DIM + tx] = f2bf(tile[tx][r]);
    }
  }
}

// ---------------- QKV GEMM: C[M][768] = A[M][256] * Bt[768][256]^T -----------
// 128x128 tile, BK=64, 4 waves (2x2). Grid 768, XCD-bijective swizzle. (Champion.)
__global__ __launch_bounds__(256) void gemm_qkv_kernel(
    const unsigned short* __restrict__ A, const unsigned short* __restrict__ Bt,
    const float* __restrict__ b0, const float* __restrict__ b1, const float* __restrict__ b2,
    unsigned short* __restrict__ C) {
  __shared__ __align__(16) char smem[32768];
  char* Asm = smem;            // [128][64] bf16, 128B rows, swizzled
  char* Bsm = smem + 16384;
  const int tid  = threadIdx.x;
  const int wid  = tid >> 6;
  const int lane = tid & 63;
  int lin = blockIdx.y * 6 + blockIdx.x;
  int swz = (lin & 7) * 96 + (lin >> 3);   // 768 blocks, bijective XCD swizzle
  const int m0 = (swz / 6) * 128;
  const int n0 = (swz % 6) * 128;
  const int wave_m = wid >> 1;
  const int wave_n = wid & 1;

  f32x4 acc[4][4] = {};

  for (int ks = 0; ks < 4; ++ks) {
    const int kk0 = ks * 64;
    __syncthreads();
#pragma unroll
    for (int it = 0; it < 4; ++it) {
      int base     = (it * 256 + wid * 64) * 16;
      int lane_lin = base + lane * 16;
      int row  = lane_lin >> 7;
      int off  = lane_lin & 127;
      int soff = off ^ ((row & 7) << 4);
      const char* ga = (const char*)(A + (size_t)(m0 + row) * K_DIM + kk0) + soff;
      const char* gb = (const char*)(Bt + (size_t)(n0 + row) * K_DIM + kk0) + soff;
      __builtin_amdgcn_global_load_lds((gptr_t)ga, (lptr_t)(Asm + base), 16, 0, 0);
      __builtin_amdgcn_global_load_lds((gptr_t)gb, (lptr_t)(Bsm + base), 16, 0, 0);
    }
    __syncthreads();

#pragma unroll
    for (int kk = 0; kk < 2; ++kk) {
      s16x8 af[4], bf[4];
#pragma unroll
      for (int m = 0; m < 4; ++m) {
        int r    = wave_m * 64 + m * 16 + (lane & 15);
        int byte = kk * 64 + ((lane >> 4) * 16);
        af[m] = *(const s16x8*)(Asm + r * 128 + (byte ^ ((r & 7) << 4)));
      }
#pragma unroll
      for (int n = 0; n < 4; ++n) {
        int r    = wave_n * 64 + n * 16 + (lane & 15);
        int byte = kk * 64 + ((lane >> 4) * 16);
        bf[n] = *(const s16x8*)(Bsm + r * 128 + (byte ^ ((r & 7) << 4)));
      }
#pragma unroll
      for (int m = 0; m < 4; ++m)
#pragma unroll
        for (int n = 0; n < 4; ++n)
          acc[m][n] = __builtin_amdgcn_mfma_f32_16x16x32_bf16(af[m], bf[n], acc[m][n], 0, 0, 0);
    }
  }

  const int c0 = lane & 15;
  const int r0 = (lane >> 4) * 4;
#pragma unroll
  for (int m = 0; m < 4; ++m) {
#pragma unroll
    for (int n = 0; n < 4; ++n) {
      int row = m0 + wave_m * 64 + m * 16 + r0;
      int col = n0 + wave_n * 64 + n * 16 + c0;
      const float* bias = (col < 256) ? b0 : (col < 512) ? b1 : b2;
      float bb = bias[col & 255];
#pragma unroll
      for (int r = 0; r < 4; ++r)
        C[(size_t)(row + r) * 768 + col] = f2bf(acc[m][n][r] + bb);
    }
  }
}

// -------- Fused local-attention + output GEMM + bias + residual --------------
// Block = one image row (32 tokens), 512 threads (8 waves). Grid 512 (2/CU).
// Phase 1: K-halo (48KB) -> LDS via global_load_lds; V (18 rows/wave) + Q -> regs
//          concurrently; ONE barrier; scores from LDS-K, softmax+PV in regs;
//          A-tile (16KB, swizzled) written to LDS.
// Phase 2: C[32][256] = A @ Wo^T, Bsm staged via global_load_lds (proven).
__global__ __launch_bounds__(512, 4) void attn_ogemm_kernel(
    const unsigned short* __restrict__ qkv, const unsigned short* __restrict__ wto,
    const float* __restrict__ bo, const float* __restrict__ x,
    float* __restrict__ out) {
  __shared__ __align__(16) char smem[65536];
  char* Halo = smem;           // 48KB: K-halo in phase 1; Bsm (32KB) in phase 2
  char* Asm  = smem + 49152;   // [32 tok][512B], XOR-swizzled
  const int tid  = threadIdx.x;
  const int wid  = tid >> 6;
  const int lane = tid & 63;
  int bswz = (blockIdx.x & 7) * 64 + (blockIdx.x >> 3);
  const int bt = bswz >> 5;
  const int h  = bswz & 31;
  const int t0 = bswz * 32;
  const size_t img = (size_t)bt << 10;

  int srow[3];
  srow[0] = max(h - 1, 0); srow[1] = h; srow[2] = min(h + 1, 31);

  // ---- Phase 1: K-halo -> LDS (48 x 1KB chunks) ----
#pragma unroll
  for (int sweep = 0; sweep < 6; ++sweep) {
    int chunk = sweep * 8 + wid;
    int slot = chunk >> 4, t2 = chunk & 15;
    int tokw = t2 * 2 + (lane >> 5);
    int off  = (lane & 31) * 16;
    size_t grow = img + (size_t)srow[slot] * 32 + tokw;
    const char* ga = (const char*)qkv + grow * 1536 + 512 + off;  // K at elem 256
    __builtin_amdgcn_global_load_lds((gptr_t)ga, (lptr_t)(Halo + chunk * 1024), 16, 0, 0);
  }
  // Concurrently: Q (4 rows) and V (18 rows: 3 srows x 6 cols) into registers.
  s16x4 qr4[4];
#pragma unroll
  for (int i = 0; i < 4; ++i)
    qr4[i] = *(const s16x4*)(qkv + (size_t)(t0 + wid * 4 + i) * 768 + lane * 4);
  s16x4 vreg[3][6];
#pragma unroll
  for (int s = 0; s < 3; ++s) {
#pragma unroll
    for (int cr = 0; cr < 6; ++cr) {
      int cc = min(max(wid * 4 - 1 + cr, 0), 31);
      vreg[s][cr] = *(const s16x4*)(qkv + (img + (size_t)srow[s] * 32 + cc) * 768 +
                                    512 + lane * 4);
    }
  }
  __syncthreads();  // drains K-halo (and V/Q loads)

  // ---- scores + softmax + PV per token; head = lane>>3, d = lane*4 ----
#pragma unroll
  for (int i = 0; i < 4; ++i) {
    int tloc = wid * 4 + i;
    f32x4 q;
#pragma unroll
    for (int e = 0; e < 4; ++e) q[e] = bf2f(qr4[i][e]);
    float sc[9];
#pragma unroll
    for (int s = 0; s < 3; ++s) {
#pragma unroll
      for (int dw = -1; dw <= 1; ++dw) {
        const int j = s * 3 + (dw + 1);
        int cw = min(max(tloc + dw, 0), 31);
        s16x4 kr = *(const s16x4*)(Halo + (s * 32 + cw) * 512 + lane * 8);
        float p = 0.f;
#pragma unroll
        for (int e = 0; e < 4; ++e) p += q[e] * bf2f(kr[e]);
        p += __shfl_xor(p, 1);
        p += __shfl_xor(p, 2);
        p += __shfl_xor(p, 4);
        sc[j] = p * 0.17677669529663687f;  // 1/sqrt(32)
      }
    }
    float mx = sc[0];
#pragma unroll
    for (int j = 1; j < 9; ++j) mx = fmaxf(mx, sc[j]);
    float den = 0.f;
#pragma unroll
    for (int j = 0; j < 9; ++j) { sc[j] = __expf(sc[j] - mx); den += sc[j]; }
    float inv = 1.0f / den;
    f32x4 o = {};
#pragma unroll
    for (int s = 0; s < 3; ++s) {
#pragma unroll
      for (int dw = -1; dw <= 1; ++dw) {
        const int j = s * 3 + (dw + 1);
        float wj = sc[j] * inv;
        s16x4 vr = vreg[s][i + dw + 1];   // static index
#pragma unroll
        for (int e = 0; e < 4; ++e) o[e] += wj * bf2f(vr[e]);
      }
    }
    s16x4 ov;
#pragma unroll
    for (int e = 0; e < 4; ++e) ov[e] = (short)f2bf(o[e]);
    int byte = (lane * 8) ^ ((tloc & 7) << 4);
    *(s16x4*)(Asm + tloc * 512 + byte) = ov;
  }

  // ---- Phase 2: out-GEMM. 8 waves = 2(m) x 4(n); wave-tile 16x64 ----
  const int wave_m = wid >> 2;
  const int wave_n = wid & 3;
  f32x4 acc[4] = {};

  for (int ks = 0; ks < 4; ++ks) {
    __syncthreads();  // Asm visible / prev Bsm reads done
#pragma unroll
    for (int it = 0; it < 4; ++it) {
      int base     = it * 8192 + wid * 1024;
      int lane_lin = base + lane * 16;
      int row  = lane_lin >> 7;   // 128B rows
      int off  = lane_lin & 127;
      int soff = off ^ ((row & 7) << 4);
      const char* gb = (const char*)(wto + (size_t)row * K_DIM + ks * 64) + soff;
      __builtin_amdgcn_global_load_lds((gptr_t)gb, (lptr_t)(Halo + base), 16, 0, 0);
    }
    __syncthreads();

#pragma unroll
    for (int kk = 0; kk < 2; ++kk) {
      s16x8 af, bf[4];
      {
        int r    = wave_m * 16 + (lane & 15);
        int byte = ks * 128 + kk * 64 + ((lane >> 4) * 16);
        af = *(const s16x8*)(Asm + r * 512 + (byte ^ ((r & 7) << 4)));
      }
#pragma unroll
      for (int n = 0; n < 4; ++n) {
        int r    = wave_n * 64 + n * 16 + (lane & 15);
        int byte = kk * 64 + ((lane >> 4) * 16);
        bf[n] = *(const s16x8*)(Halo + r * 128 + (byte ^ ((r & 7) << 4)));
      }
#pragma unroll
      for (int n = 0; n < 4; ++n)
        acc[n] = __builtin_amdgcn_mfma_f32_16x16x32_bf16(af, bf[n], acc[n], 0, 0, 0);
    }
  }

  const int c0 = lane & 15;
  const int r0 = (lane >> 4) * 4;
#pragma unroll
  for (int n = 0; n < 4; ++n) {
    int col = wave_n * 64 + n * 16 + c0;
    float bb = bo[col];
#pragma unroll
    for (int r = 0; r < 4; ++r) {
      int row = t0 + wave_m * 16 + r0 + r;
      out[(size_t)row * D_ + col] = acc[n][r] + bb + x[(size_t)row * D_ + col];
    }
  }
}

extern "C" void kernel_launch(void* const* d_in, const int* in_sizes, int n_in,
                              void* d_out, int out_size, void* d_ws, size_t ws_size,
                              hipStream_t stream) {
  const float* x  = (const float*)d_in[0];
  const float* lg = (const float*)d_in[1];
  const float* lb = (const float*)d_in[2];
  const float* wq = (const float*)d_in[3];
  const float* bq = (const float*)d_in[4];
  const float* wk = (const float*)d_in[5];
  const float* bk = (const float*)d_in[6];
  const float* wv = (const float*)d_in[7];
  const float* bv = (const float*)d_in[8];
  const float* wo = (const float*)d_in[9];
  const float* bo = (const float*)d_in[10];
  float* out = (float*)d_out;

  char* ws = (char*)d_ws;
  unsigned short* xn    = (unsigned short*)ws;                 // 16384*256*2
  unsigned short* qkv   = (unsigned short*)(ws + 8388608);     // 16384*768*2
  unsigned short* wtqkv = (unsigned short*)(ws + 33554432);    // 768*256*2
  unsigned short* wto   = (unsigned short*)(ws + 33947648);    // 256*256*2

  prep_kernel<<<4352, 256, 0, stream>>>(x, lg, lb, xn, wq, wk, wv, wo, wtqkv, wto);
  gemm_qkv_kernel<<<dim3(6, 128), 256, 0, stream>>>(xn, wtqkv, bq, bk, bv, qkv);
  attn_ogemm_kernel<<<512, 512, 0, stream>>>(qkv, wto, bo, x, out);
}

// Round 15
// 39.583 us; speedup vs baseline: 1.5257x; 1.0439x over previous
//
#include <hip/hip_runtime.h>
#include <hip/hip_bf16.h>

#define M_TOT 16384   // B*T*H*W = 2*8*32*32
#define D_    256
#define K_DIM 256

typedef __attribute__((ext_vector_type(4))) float f32x4;
typedef __attribute__((ext_vector_type(8))) short s16x8;
typedef __attribute__((ext_vector_type(4))) short s16x4;

typedef const __attribute__((address_space(1))) void* gptr_t;
typedef __attribute__((address_space(3))) void* lptr_t;

__device__ __forceinline__ unsigned short f2bf(float f) {
  unsigned x = __float_as_uint(f);
  return (unsigned short)((x + 0x7fffu + ((x >> 16) & 1u)) >> 16);
}
__device__ __forceinline__ float bf2f(short s) {
  return __uint_as_float(((unsigned)(unsigned short)s) << 16);
}

// ---------- prep: blocks [0,4096) = LayerNorm, [4096,4352) = weight transpose ----------
__global__ __launch_bounds__(256) void prep_kernel(
    const float* __restrict__ x, const float* __restrict__ g, const float* __restrict__ b,
    unsigned short* __restrict__ xn,
    const float* __restrict__ wq, const float* __restrict__ wk,
    const float* __restrict__ wv, const float* __restrict__ wo,
    unsigned short* __restrict__ wt_qkv, unsigned short* __restrict__ wt_o) {
  __shared__ float tile[32][33];
  int tid = threadIdx.x;
  if (blockIdx.x < 4096) {
    int tok  = blockIdx.x * 4 + (tid >> 6);
    int lane = tid & 63;
    f32x4 v = ((const f32x4*)(x + (size_t)tok * D_))[lane];
    float s = 0.f, s2 = 0.f;
#pragma unroll
    for (int i = 0; i < 4; ++i) { s += v[i]; s2 += v[i] * v[i]; }
#pragma unroll
    for (int o = 1; o < 64; o <<= 1) { s += __shfl_xor(s, o); s2 += __shfl_xor(s2, o); }
    float mu   = s * (1.0f / 256.0f);
    float rstd = rsqrtf(s2 * (1.0f / 256.0f) - mu * mu + 1e-5f);
    f32x4 gv = ((const f32x4*)g)[lane];
    f32x4 bv = ((const f32x4*)b)[lane];
    s16x4 o4;
#pragma unroll
    for (int i = 0; i < 4; ++i) o4[i] = (short)f2bf((v[i] - mu) * rstd * gv[i] + bv[i]);
    ((s16x4*)(xn + (size_t)tok * D_))[lane] = o4;
  } else {
    int bid = blockIdx.x - 4096;     // 0..255
    int z   = bid >> 6;              // 0=wq 1=wk 2=wv 3=wo
    int rem = bid & 63;
    int k0 = (rem & 7) * 32, n0 = (rem >> 3) * 32;
    int tx = tid & 31, ty = tid >> 5;  // (32,8)
    const float* src = (z == 0) ? wq : (z == 1) ? wk : (z == 2) ? wv : wo;
#pragma unroll
    for (int i = 0; i < 4; ++i) {
      int r = ty + i * 8;
      tile[r][tx] = src[(size_t)(k0 + r) * D_ + n0 + tx];
    }
    __syncthreads();
    unsigned short* dst = (z < 3) ? (wt_qkv + (size_t)(z * 256 + n0) * K_DIM + k0)
                                  : (wt_o + (size_t)n0 * K_DIM + k0);
#pragma unroll
    for (int i = 0; i < 4; ++i) {
      int r = ty + i * 8;
      dst[(size_t)r * K_DIM + tx] = f2bf(tile[tx][r]);
    }
  }
}

// ---------------- QKV GEMM: C[M][768] = A[M][256] * Bt[768][256]^T -----------
// 128x128 tile, BK=64, 4 waves (2x2). Grid 768, XCD-bijective swizzle. (Champion.)
__global__ __launch_bounds__(256) void gemm_qkv_kernel(
    const unsigned short* __restrict__ A, const unsigned short* __restrict__ Bt,
    const float* __restrict__ b0, const float* __restrict__ b1, const float* __restrict__ b2,
    unsigned short* __restrict__ C) {
  __shared__ __align__(16) char smem[32768];
  char* Asm = smem;            // [128][64] bf16, 128B rows, swizzled
  char* Bsm = smem + 16384;
  const int tid  = threadIdx.x;
  const int wid  = tid >> 6;
  const int lane = tid & 63;
  int lin = blockIdx.y * 6 + blockIdx.x;
  int swz = (lin & 7) * 96 + (lin >> 3);   // 768 blocks, bijective XCD swizzle
  const int m0 = (swz / 6) * 128;
  const int n0 = (swz % 6) * 128;
  const int wave_m = wid >> 1;
  const int wave_n = wid & 1;

  f32x4 acc[4][4] = {};

  for (int ks = 0; ks < 4; ++ks) {
    const int kk0 = ks * 64;
    __syncthreads();
#pragma unroll
    for (int it = 0; it < 4; ++it) {
      int base     = (it * 256 + wid * 64) * 16;
      int lane_lin = base + lane * 16;
      int row  = lane_lin >> 7;
      int off  = lane_lin & 127;
      int soff = off ^ ((row & 7) << 4);
      const char* ga = (const char*)(A + (size_t)(m0 + row) * K_DIM + kk0) + soff;
      const char* gb = (const char*)(Bt + (size_t)(n0 + row) * K_DIM + kk0) + soff;
      __builtin_amdgcn_global_load_lds((gptr_t)ga, (lptr_t)(Asm + base), 16, 0, 0);
      __builtin_amdgcn_global_load_lds((gptr_t)gb, (lptr_t)(Bsm + base), 16, 0, 0);
    }
    __syncthreads();

#pragma unroll
    for (int kk = 0; kk < 2; ++kk) {
      s16x8 af[4], bf[4];
#pragma unroll
      for (int m = 0; m < 4; ++m) {
        int r    = wave_m * 64 + m * 16 + (lane & 15);
        int byte = kk * 64 + ((lane >> 4) * 16);
        af[m] = *(const s16x8*)(Asm + r * 128 + (byte ^ ((r & 7) << 4)));
      }
#pragma unroll
      for (int n = 0; n < 4; ++n) {
        int r    = wave_n * 64 + n * 16 + (lane & 15);
        int byte = kk * 64 + ((lane >> 4) * 16);
        bf[n] = *(const s16x8*)(Bsm + r * 128 + (byte ^ ((r & 7) << 4)));
      }
#pragma unroll
      for (int m = 0; m < 4; ++m)
#pragma unroll
        for (int n = 0; n < 4; ++n)
          acc[m][n] = __builtin_amdgcn_mfma_f32_16x16x32_bf16(af[m], bf[n], acc[m][n], 0, 0, 0);
    }
  }

  const int c0 = lane & 15;
  const int r0 = (lane >> 4) * 4;
#pragma unroll
  for (int m = 0; m < 4; ++m) {
#pragma unroll
    for (int n = 0; n < 4; ++n) {
      int row = m0 + wave_m * 64 + m * 16 + r0;
      int col = n0 + wave_n * 64 + n * 16 + c0;
      const float* bias = (col < 256) ? b0 : (col < 512) ? b1 : b2;
      float bb = bias[col & 255];
#pragma unroll
      for (int r = 0; r < 4; ++r)
        C[(size_t)(row + r) * 768 + col] = f2bf(acc[m][n][r] + bb);
    }
  }
}

// -------- Fused local-attention + output GEMM + bias + residual --------------
// Block = one image row (32 tokens), 512 threads (8 waves). Grid 512 (2/CU).
// Phase 1: K AND V in per-wave registers (18 rows each, coalesced 512B/row);
//          NO block barrier for attention inputs (per-wave vmcnt only);
//          Bsm for ks=0 prefetched via global_load_lds under phase 1.
// Phase 2: C[32][256] = Asm @ Wo^T; LDS = Asm 16KB + Bsm 32KB = 48KB.
__global__ __launch_bounds__(512, 4) void attn_ogemm_kernel(
    const unsigned short* __restrict__ qkv, const unsigned short* __restrict__ wto,
    const float* __restrict__ bo, const float* __restrict__ x,
    float* __restrict__ out) {
  __shared__ __align__(16) char smem[49152];
  char* Asm = smem;            // [32 tok][512B], XOR-swizzled
  char* Bsm = smem + 16384;    // [128][128B] Wo K-slice, swizzled
  const int tid  = threadIdx.x;
  const int wid  = tid >> 6;
  const int lane = tid & 63;
  int bswz = (blockIdx.x & 7) * 64 + (blockIdx.x >> 3);
  const int bt = bswz >> 5;
  const int h  = bswz & 31;
  const int t0 = bswz * 32;
  const size_t img = (size_t)bt << 10;

  int srow[3];
  srow[0] = max(h - 1, 0); srow[1] = h; srow[2] = min(h + 1, 31);

  // ---- prefetch Bsm for ks=0 (hidden under all of phase 1) ----
#pragma unroll
  for (int it = 0; it < 4; ++it) {
    int base     = it * 8192 + wid * 1024;
    int lane_lin = base + lane * 16;
    int row  = lane_lin >> 7;
    int off  = lane_lin & 127;
    int soff = off ^ ((row & 7) << 4);
    const char* gb = (const char*)(wto + (size_t)row * K_DIM + 0) + soff;
    __builtin_amdgcn_global_load_lds((gptr_t)gb, (lptr_t)(Bsm + base), 16, 0, 0);
  }

  // ---- per-wave register loads: Q (4 rows), K (3x6), V (3x6) — coalesced ----
  s16x4 qr4[4];
#pragma unroll
  for (int i = 0; i < 4; ++i)
    qr4[i] = *(const s16x4*)(qkv + (size_t)(t0 + wid * 4 + i) * 768 + lane * 4);
  s16x4 kreg[3][6], vreg[3][6];
#pragma unroll
  for (int s = 0; s < 3; ++s) {
#pragma unroll
    for (int cr = 0; cr < 6; ++cr) {
      int cc = min(max(wid * 4 - 1 + cr, 0), 31);
      const unsigned short* rowp = qkv + (img + (size_t)srow[s] * 32 + cc) * 768;
      kreg[s][cr] = *(const s16x4*)(rowp + 256 + lane * 4);
      vreg[s][cr] = *(const s16x4*)(rowp + 512 + lane * 4);
    }
  }

  // ---- scores + softmax + PV per token, all from registers ----
#pragma unroll
  for (int i = 0; i < 4; ++i) {
    f32x4 q;
#pragma unroll
    for (int e = 0; e < 4; ++e) q[e] = bf2f(qr4[i][e]);
    float sc[9];
#pragma unroll
    for (int s = 0; s < 3; ++s) {
#pragma unroll
      for (int dw = -1; dw <= 1; ++dw) {
        const int j = s * 3 + (dw + 1);
        s16x4 kr = kreg[s][i + dw + 1];   // static index; cc pre-clamped at load
        float p = 0.f;
#pragma unroll
        for (int e = 0; e < 4; ++e) p += q[e] * bf2f(kr[e]);
        p += __shfl_xor(p, 1);
        p += __shfl_xor(p, 2);
        p += __shfl_xor(p, 4);
        sc[j] = p * 0.17677669529663687f;  // 1/sqrt(32)
      }
    }
    float mx = sc[0];
#pragma unroll
    for (int j = 1; j < 9; ++j) mx = fmaxf(mx, sc[j]);
    float den = 0.f;
#pragma unroll
    for (int j = 0; j < 9; ++j) { sc[j] = __expf(sc[j] - mx); den += sc[j]; }
    float inv = 1.0f / den;
    f32x4 o = {};
#pragma unroll
    for (int s = 0; s < 3; ++s) {
#pragma unroll
      for (int dw = -1; dw <= 1; ++dw) {
        const int j = s * 3 + (dw + 1);
        float wj = sc[j] * inv;
        s16x4 vr = vreg[s][i + dw + 1];   // static index
#pragma unroll
        for (int e = 0; e < 4; ++e) o[e] += wj * bf2f(vr[e]);
      }
    }
    int tloc = wid * 4 + i;
    s16x4 ov;
#pragma unroll
    for (int e = 0; e < 4; ++e) ov[e] = (short)f2bf(o[e]);
    int byte = (lane * 8) ^ ((tloc & 7) << 4);
    *(s16x4*)(Asm + tloc * 512 + byte) = ov;
  }
  __syncthreads();  // Asm visible + Bsm(ks=0) staged

  // ---- Phase 2: out-GEMM. 8 waves = 2(m) x 4(n); wave-tile 16x64 ----
  const int wave_m = wid >> 2;
  const int wave_n = wid & 3;
  f32x4 acc[4] = {};

  for (int ks = 0; ks < 4; ++ks) {
#pragma unroll
    for (int kk = 0; kk < 2; ++kk) {
      s16x8 af, bf[4];
      {
        int r    = wave_m * 16 + (lane & 15);
        int byte = ks * 128 + kk * 64 + ((lane >> 4) * 16);
        af = *(const s16x8*)(Asm + r * 512 + (byte ^ ((r & 7) << 4)));
      }
#pragma unroll
      for (int n = 0; n < 4; ++n) {
        int r    = wave_n * 64 + n * 16 + (lane & 15);
        int byte = kk * 64 + ((lane >> 4) * 16);
        bf[n] = *(const s16x8*)(Bsm + r * 128 + (byte ^ ((r & 7) << 4)));
      }
#pragma unroll
      for (int n = 0; n < 4; ++n)
        acc[n] = __builtin_amdgcn_mfma_f32_16x16x32_bf16(af, bf[n], acc[n], 0, 0, 0);
    }
    if (ks < 3) {
      __syncthreads();  // all Bsm reads done
#pragma unroll
      for (int it = 0; it < 4; ++it) {
        int base     = it * 8192 + wid * 1024;
        int lane_lin = base + lane * 16;
        int row  = lane_lin >> 7;
        int off  = lane_lin & 127;
        int soff = off ^ ((row & 7) << 4);
        const char* gb = (const char*)(wto + (size_t)row * K_DIM + (ks + 1) * 64) + soff;
        __builtin_amdgcn_global_load_lds((gptr_t)gb, (lptr_t)(Bsm + base), 16, 0, 0);
      }
      __syncthreads();  // staged
    }
  }

  const int c0 = lane & 15;
  const int r0 = (lane >> 4) * 4;
#pragma unroll
  for (int n = 0; n < 4; ++n) {
    int col = wave_n * 64 + n * 16 + c0;
    float bb = bo[col];
#pragma unroll
    for (int r = 0; r < 4; ++r) {
      int row = t0 + wave_m * 16 + r0 + r;
      out[(size_t)row * D_ + col] = acc[n][r] + bb + x[(size_t)row * D_ + col];
    }
  }
}

extern "C" void kernel_launch(void* const* d_in, const int* in_sizes, int n_in,
                              void* d_out, int out_size, void* d_ws, size_t ws_size,
                              hipStream_t stream) {
  const float* x  = (const float*)d_in[0];
  const float* lg = (const float*)d_in[1];
  const float* lb = (const float*)d_in[2];
  const float* wq = (const float*)d_in[3];
  const float* bq = (const float*)d_in[4];
  const float* wk = (const float*)d_in[5];
  const float* bk = (const float*)d_in[6];
  const float* wv = (const float*)d_in[7];
  const float* bv = (const float*)d_in[8];
  const float* wo = (const float*)d_in[9];
  const float* bo = (const float*)d_in[10];
  float* out = (float*)d_out;

  char* ws = (char*)d_ws;
  unsigned short* xn    = (unsigned short*)ws;                 // 16384*256*2
  unsigned short* qkv   = (unsigned short*)(ws + 8388608);     // 16384*768*2
  unsigned short* wtqkv = (unsigned short*)(ws + 33554432);    // 768*256*2
  unsigned short* wto   = (unsigned short*)(ws + 33947648);    // 256*256*2

  prep_kernel<<<4352, 256, 0, stream>>>(x, lg, lb, xn, wq, wk, wv, wo, wtqkv, wto);
  gemm_qkv_kernel<<<dim3(6, 128), 256, 0, stream>>>(xn, wtqkv, bq, bk, bv, qkv);
  attn_ogemm_kernel<<<512, 512, 0, stream>>>(qkv, wto, bo, x, out);
}